// Round 1
// baseline (4417.030 us; speedup 1.0000x reference)
//
#include <hip/hip_runtime.h>
#include <hip/hip_bf16.h>
#include <math.h>

#define N_TOK 16384
#define DIM   1024
#define HID   4096
#define NEXP  8
#define NPROJ 256
#define CLAMP_MAXD 4.605170185988091

// tile bookkeeping: sum_e ceil(cnt_e/128) <= 32768/128 + 8 = 264 tiles
#define MAX_TILES 264
#define MAX_ROWS (MAX_TILES*128)      // 33792
#define CHUNK_TILES 66
#define NCHUNK 4
#define CHUNK_ROWS (CHUNK_TILES*128)  // 8448

// meta[] layout (ints)
#define M_CNT   0   // [8] expert counts
#define M_CUR   8   // [8] fill cursors
#define M_ROWST 16  // [9] padded segment row starts
#define M_TILEST 25 // [9] segment tile starts
#define M_TOT   34  // total row tiles

typedef __bf16 bf16x8 __attribute__((ext_vector_type(8)));
typedef float  floatx4 __attribute__((ext_vector_type(4)));

__device__ __forceinline__ unsigned short f2bfbits(float f) {
  __hip_bfloat16 b = __float2bfloat16(f);
  union { __hip_bfloat16 b; unsigned short u; } c; c.b = b; return c.u;
}
__device__ __forceinline__ float bf2f(unsigned short u) {
  union { unsigned int u; float f; } c; c.u = ((unsigned int)u) << 16; return c.f;
}
__device__ __forceinline__ float gelu_exact(float z) {
  return 0.5f * z * (1.0f + erff(z * 0.70710678118654752f));
}

// ---------------- small prep kernels ----------------

__global__ void k_zero_meta(int* meta) { meta[threadIdx.x] = 0; }

// sim (PROJ,E) fp32 -> simn (PROJ,E) fp64, columns l2-normalized
__global__ __launch_bounds__(256) void k_simn(const float* __restrict__ sim,
                                              double* __restrict__ simn) {
  __shared__ double norms[NEXP];
  int t = threadIdx.x;
  if (t < NEXP) {
    double s = 0.0;
    for (int j = 0; j < NPROJ; ++j) { double v = (double)sim[j*NEXP + t]; s += v*v; }
    double n = sqrt(s); norms[t] = (n > 1e-12 ? n : 1e-12);
  }
  __syncthreads();
  for (int q = 0; q < (NPROJ*NEXP)/256; ++q) {
    int idx = t + q*256; int e = idx & (NEXP-1);
    simn[idx] = (double)sim[idx] / norms[e];
  }
}

__global__ __launch_bounds__(256) void k_cvtx(const float* __restrict__ x,
                                              unsigned short* __restrict__ xbf) {
  const int n4 = N_TOK*DIM/4;
  for (int i = blockIdx.x*blockDim.x + threadIdx.x; i < n4; i += gridDim.x*blockDim.x) {
    float4 v = ((const float4*)x)[i];
    ushort4 o; o.x = f2bfbits(v.x); o.y = f2bfbits(v.y); o.z = f2bfbits(v.z); o.w = f2bfbits(v.w);
    ((ushort4*)xbf)[i] = o;
  }
}

// fp32 (Z,R,C) -> bf16 (Z,C,R)
__global__ __launch_bounds__(256) void k_transpose(const float* __restrict__ in,
                                                   unsigned short* __restrict__ out,
                                                   int R, int C) {
  __shared__ float tile[32][33];
  size_t zoff = (size_t)blockIdx.z * (size_t)R * (size_t)C;
  in += zoff; out += zoff;
  int c  = blockIdx.x*32 + threadIdx.x;
  int r0 = blockIdx.y*32 + threadIdx.y;
  #pragma unroll
  for (int i = 0; i < 4; ++i)
    tile[threadIdx.y + i*8][threadIdx.x] = in[(size_t)(r0 + i*8)*C + c];
  __syncthreads();
  int r  = blockIdx.y*32 + threadIdx.x;
  int c0 = blockIdx.x*32 + threadIdx.y;
  #pragma unroll
  for (int i = 0; i < 4; ++i)
    out[(size_t)(c0 + i*8)*R + r] = f2bfbits(tile[threadIdx.x][threadIdx.y + i*8]);
}

// ---------------- gating (fp64 accumulation: top-k flip safety) ----------------
#define GT 8
__global__ __launch_bounds__(256) void k_gating(const float* __restrict__ x,
    const float* __restrict__ Wp, const float* __restrict__ bp,
    const double* __restrict__ simn, const float* __restrict__ temp,
    float* __restrict__ gates, int* __restrict__ eidx, int* __restrict__ meta) {
  __shared__ float xs[GT*DIM];
  __shared__ double wred[4][GT][9];
  int tid = threadIdx.x, lane = tid & 63, wv = tid >> 6;
  int i0 = blockIdx.x * GT;
  { const float4* src = (const float4*)(x + (size_t)i0*DIM);
    float4* dst = (float4*)xs;
    #pragma unroll
    for (int q = 0; q < GT*DIM/4/256; ++q) dst[tid + q*256] = src[tid + q*256]; }
  __syncthreads();
  double acc[GT];
  #pragma unroll
  for (int t = 0; t < GT; ++t) acc[t] = 0.0;
  const int j = tid; // proj column
  for (int d = 0; d < DIM; d += 4) {
    double w0 = (double)Wp[(d+0)*NPROJ + j];
    double w1 = (double)Wp[(d+1)*NPROJ + j];
    double w2 = (double)Wp[(d+2)*NPROJ + j];
    double w3 = (double)Wp[(d+3)*NPROJ + j];
    #pragma unroll
    for (int t = 0; t < GT; ++t) {
      float4 xv = *(const float4*)&xs[t*DIM + d];
      acc[t] += w0*(double)xv.x; acc[t] += w1*(double)xv.y;
      acc[t] += w2*(double)xv.z; acc[t] += w3*(double)xv.w;
    }
  }
  double bpj = (double)bp[j];
  double sn[NEXP];
  #pragma unroll
  for (int e = 0; e < NEXP; ++e) sn[e] = simn[j*NEXP + e];
  for (int t = 0; t < GT; ++t) {
    double v = acc[t] + bpj;
    double vals[9];
    vals[0] = v*v;
    #pragma unroll
    for (int e = 0; e < NEXP; ++e) vals[e+1] = v*sn[e];
    #pragma unroll
    for (int off = 32; off > 0; off >>= 1)
      #pragma unroll
      for (int k = 0; k < 9; ++k) vals[k] += __shfl_down(vals[k], off, 64);
    if (lane == 0)
      #pragma unroll
      for (int k = 0; k < 9; ++k) wred[wv][t][k] = vals[k];
  }
  __syncthreads();
  if (tid < GT) {
    int t = tid;
    double s[9];
    #pragma unroll
    for (int k = 0; k < 9; ++k)
      s[k] = wred[0][t][k] + wred[1][t][k] + wred[2][t][k] + wred[3][t][k];
    double den = sqrt(s[0]); if (den < 1e-12) den = 1e-12;
    double tp = (double)temp[0]; if (tp > CLAMP_MAXD) tp = CLAMP_MAXD;
    double sc = exp(tp) / den;
    double l[NEXP];
    #pragma unroll
    for (int e = 0; e < NEXP; ++e) l[e] = s[e+1]*sc;
    int iA = 0; double vA = l[0];
    for (int e = 1; e < NEXP; ++e) if (l[e] > vA) { vA = l[e]; iA = e; }
    int iB = -1; double vB = -1e300;
    for (int e = 0; e < NEXP; ++e) if (e != iA && l[e] > vB) { vB = l[e]; iB = e; }
    double ex = exp(vB - vA);
    double g0 = 1.0/(1.0+ex);
    int i = i0 + t;
    gates[2*i] = (float)g0; gates[2*i+1] = (float)(ex/(1.0+ex));
    eidx[2*i] = iA; eidx[2*i+1] = iB;
    atomicAdd(&meta[M_CNT + iA], 1); atomicAdd(&meta[M_CNT + iB], 1);
  }
}

// ---------------- routing ----------------
__global__ void k_offsets(int* meta) {
  int accT = 0;
  for (int e = 0; e < NEXP; ++e) {
    meta[M_TILEST + e] = accT;
    meta[M_ROWST + e]  = accT * 128;
    accT += (meta[M_CNT + e] + 127) >> 7;
  }
  meta[M_TILEST + NEXP] = accT;
  meta[M_ROWST + NEXP]  = accT * 128;
  meta[M_TOT] = accT;
}

__global__ void k_inittok(int* tok) { tok[blockIdx.x*256 + threadIdx.x] = 0; }

__global__ void k_fill(const int* __restrict__ eidx, int* meta,
                       int* __restrict__ tok, int* __restrict__ rowOf) {
  int i = blockIdx.x*256 + threadIdx.x;
  if (i >= N_TOK) return;
  #pragma unroll
  for (int k = 0; k < 2; ++k) {
    int e = eidx[2*i + k];
    int pos = atomicAdd(&meta[M_CUR + e], 1);
    int row = meta[M_ROWST + e] + pos;
    tok[row] = i;
    rowOf[2*i + k] = row;
  }
}

// ---------------- expert GEMM: 128x128 tile, BK=64, bf16 MFMA 16x16x32 ----------------
union LdsU {
  struct { short A[128][72]; short B[128][72]; } s;  // pad 64->72 shorts: conflict-free frags
  float C[32*132];                                    // epilogue transpose buffer
};

template<int ACT>
__global__ __launch_bounds__(256) void k_gemm(
    const unsigned short* __restrict__ Abase, const int* __restrict__ rowmap, int aRowOff,
    const unsigned short* __restrict__ Bbase, long bExpStride,
    const float* __restrict__ biasBase, int biasStride,
    unsigned short* __restrict__ Cbase, int ldc, int cRowOff,
    const int* __restrict__ meta, int tileBase, int K) {
  __shared__ LdsU lds;
  int rt = tileBase + blockIdx.y;
  if (rt >= meta[M_TOT]) return;
  int e = 0;
  #pragma unroll
  for (int q = 1; q < NEXP; ++q) if (rt >= meta[M_TILEST + q]) e = q;
  const unsigned short* Bexp = Bbase + (size_t)e * (size_t)bExpStride;
  int tid = threadIdx.x;
  int lane = tid & 63, wv = tid >> 6, mw = wv >> 1, nw = wv & 1;
  int ntBase = blockIdx.x * 128;
  int r0 = tid >> 3, g = tid & 7;
  const unsigned short* aptr[4]; const unsigned short* bptr[4];
  #pragma unroll
  for (int i = 0; i < 4; ++i) {
    int r = r0 + i*32;
    int grow = rt*128 + r;
    int arow = rowmap ? rowmap[grow] : (grow - aRowOff);
    aptr[i] = Abase + (size_t)arow * (size_t)K + g*8;
    bptr[i] = Bexp + (size_t)(ntBase + r) * (size_t)K + g*8;
  }
  floatx4 acc[4][4];
  #pragma unroll
  for (int mi = 0; mi < 4; ++mi)
    #pragma unroll
    for (int ni = 0; ni < 4; ++ni) acc[mi][ni] = (floatx4){0.f,0.f,0.f,0.f};
  const int nK = K >> 6;
  for (int kt = 0; kt < nK; ++kt) {
    int4 av[4], bv[4];
    #pragma unroll
    for (int i = 0; i < 4; ++i) av[i] = *(const int4*)(aptr[i] + (kt<<6));
    #pragma unroll
    for (int i = 0; i < 4; ++i) bv[i] = *(const int4*)(bptr[i] + (kt<<6));
    __syncthreads();
    #pragma unroll
    for (int i = 0; i < 4; ++i) {
      *(int4*)&lds.s.A[r0 + i*32][g*8] = av[i];
      *(int4*)&lds.s.B[r0 + i*32][g*8] = bv[i];
    }
    __syncthreads();
    #pragma unroll
    for (int ks = 0; ks < 2; ++ks) {
      int koff = ks*32 + ((lane>>4)<<3);
      bf16x8 af[4], bfr[4];
      #pragma unroll
      for (int mi = 0; mi < 4; ++mi)
        af[mi] = *(const bf16x8*)&lds.s.A[mw*64 + mi*16 + (lane&15)][koff];
      #pragma unroll
      for (int ni = 0; ni < 4; ++ni)
        bfr[ni] = *(const bf16x8*)&lds.s.B[nw*64 + ni*16 + (lane&15)][koff];
      #pragma unroll
      for (int mi = 0; mi < 4; ++mi)
        #pragma unroll
        for (int ni = 0; ni < 4; ++ni)
          acc[mi][ni] = __builtin_amdgcn_mfma_f32_16x16x32_bf16(af[mi], bfr[ni], acc[mi][ni], 0,0,0);
    }
  }
  // epilogue: per m-subtile, LDS transpose -> bias -> (gelu) -> bf16 coalesced store
  const float* bias = biasBase + (size_t)e * (size_t)biasStride + ntBase;
  #pragma unroll
  for (int p = 0; p < 4; ++p) {
    __syncthreads();
    int lrow0 = mw*16 + ((lane>>4)<<2);
    int lcol  = nw*64 + (lane & 15);
    #pragma unroll
    for (int ni = 0; ni < 4; ++ni)
      #pragma unroll
      for (int jj = 0; jj < 4; ++jj)
        lds.C[(lrow0 + jj)*132 + lcol + ni*16] = acc[p][ni][jj];
    __syncthreads();
    #pragma unroll
    for (int q = 0; q < 4; ++q) {
      int lin = tid + q*256;
      int r = lin >> 5, c4 = lin & 31;
      float4 v = *(float4*)&lds.C[r*132 + c4*4];
      float4 b4 = *(const float4*)&bias[c4*4];
      v.x += b4.x; v.y += b4.y; v.z += b4.z; v.w += b4.w;
      if (ACT == 1) { v.x = gelu_exact(v.x); v.y = gelu_exact(v.y); v.z = gelu_exact(v.z); v.w = gelu_exact(v.w); }
      int gm = rt*128 + (r>>4)*64 + p*16 + (r&15) - cRowOff;
      ushort4 o; o.x = f2bfbits(v.x); o.y = f2bfbits(v.y); o.z = f2bfbits(v.z); o.w = f2bfbits(v.w);
      *(ushort4*)&Cbase[(size_t)gm*(size_t)ldc + ntBase + c4*4] = o;
    }
  }
}

// ---------------- combine: out = x + g0*f[r0] + g1*f[r1] ----------------
__global__ __launch_bounds__(256) void k_combine(const float* __restrict__ x,
    const unsigned short* __restrict__ f, const int* __restrict__ rowOf,
    const float* __restrict__ gates, float* __restrict__ out) {
  int i = blockIdx.x, t = threadIdx.x;
  int r0 = rowOf[2*i], r1 = rowOf[2*i+1];
  float g0 = gates[2*i], g1 = gates[2*i+1];
  float4 xv = ((const float4*)(x + (size_t)i*DIM))[t];
  ushort4 a = ((const ushort4*)(f + (size_t)r0*DIM))[t];
  ushort4 b = ((const ushort4*)(f + (size_t)r1*DIM))[t];
  float4 o;
  o.x = xv.x + g0*bf2f(a.x) + g1*bf2f(b.x);
  o.y = xv.y + g0*bf2f(a.y) + g1*bf2f(b.y);
  o.z = xv.z + g0*bf2f(a.z) + g1*bf2f(b.z);
  o.w = xv.w + g0*bf2f(a.w) + g1*bf2f(b.w);
  ((float4*)(out + (size_t)i*DIM))[t] = o;
}

// ---------------- launch ----------------
extern "C" void kernel_launch(void* const* d_in, const int* in_sizes, int n_in,
                              void* d_out, int out_size, void* d_ws, size_t ws_size,
                              hipStream_t stream) {
  const float* x    = (const float*)d_in[0];
  const float* Wp   = (const float*)d_in[1];
  const float* bp   = (const float*)d_in[2];
  const float* sim  = (const float*)d_in[3];
  const float* temp = (const float*)d_in[4];
  const float* W1   = (const float*)d_in[5];
  const float* b1   = (const float*)d_in[6];
  const float* W2   = (const float*)d_in[7];
  const float* b2   = (const float*)d_in[8];
  float* out = (float*)d_out;

  // workspace carve (~307 MB total)
  char* w = (char*)d_ws;
  auto carve = [&](size_t bytes) { char* p = w; w += (bytes + 255) & ~(size_t)255; return p; };
  int*            meta = (int*)           carve(64*sizeof(int));
  float*          gates= (float*)         carve((size_t)N_TOK*2*4);
  int*            eidx = (int*)           carve((size_t)N_TOK*2*4);
  int*            rowOf= (int*)           carve((size_t)N_TOK*2*4);
  int*            tok  = (int*)           carve((size_t)MAX_ROWS*4);
  double*         simn = (double*)        carve((size_t)NPROJ*NEXP*8);
  unsigned short* xbf  = (unsigned short*)carve((size_t)N_TOK*DIM*2);
  unsigned short* W1t  = (unsigned short*)carve((size_t)NEXP*HID*DIM*2);
  unsigned short* W2t  = (unsigned short*)carve((size_t)NEXP*DIM*HID*2);
  unsigned short* h    = (unsigned short*)carve((size_t)CHUNK_ROWS*HID*2);
  unsigned short* f    = (unsigned short*)carve((size_t)MAX_ROWS*DIM*2);

  hipLaunchKernelGGL(k_zero_meta, dim3(1), dim3(64), 0, stream, meta);
  hipLaunchKernelGGL(k_simn, dim3(1), dim3(256), 0, stream, sim, simn);
  hipLaunchKernelGGL(k_cvtx, dim3(2048), dim3(256), 0, stream, x, xbf);
  // W1 (E, D, H) -> W1t (E, H, D);  W2 (E, H, D) -> W2t (E, D, H)
  hipLaunchKernelGGL(k_transpose, dim3(HID/32, DIM/32, NEXP), dim3(32,8), 0, stream, W1, W1t, DIM, HID);
  hipLaunchKernelGGL(k_transpose, dim3(DIM/32, HID/32, NEXP), dim3(32,8), 0, stream, W2, W2t, HID, DIM);
  hipLaunchKernelGGL(k_gating, dim3(N_TOK/GT), dim3(256), 0, stream, x, Wp, bp, simn, temp, gates, eidx, meta);
  hipLaunchKernelGGL(k_offsets, dim3(1), dim3(1), 0, stream, meta);
  hipLaunchKernelGGL(k_inittok, dim3(MAX_ROWS/256), dim3(256), 0, stream, tok);
  hipLaunchKernelGGL(k_fill, dim3(N_TOK/256), dim3(256), 0, stream, eidx, meta, tok, rowOf);
  for (int c = 0; c < NCHUNK; ++c) {
    // GEMM1: h = gelu(gather(xbf) @ W1t[e]^T + b1[e]);  grid x = H tiles, y = row tiles
    hipLaunchKernelGGL((k_gemm<1>), dim3(HID/128, CHUNK_TILES), dim3(256), 0, stream,
        xbf, tok, 0, W1t, (long)HID*DIM, b1, HID,
        h, HID, c*CHUNK_ROWS, meta, c*CHUNK_TILES, DIM);
    // GEMM2: f = h @ W2t[e]^T + b2[e]
    hipLaunchKernelGGL((k_gemm<0>), dim3(DIM/128, CHUNK_TILES), dim3(256), 0, stream,
        h, (const int*)nullptr, c*CHUNK_ROWS, W2t, (long)DIM*HID, b2, DIM,
        f, DIM, 0, meta, c*CHUNK_TILES, HID);
  }
  hipLaunchKernelGGL(k_combine, dim3(N_TOK), dim3(256), 0, stream, x, f, rowOf, gates, out);
}

// Round 2
// 2661.150 us; speedup vs baseline: 1.6598x; 1.6598x over previous
//
#include <hip/hip_runtime.h>
#include <hip/hip_bf16.h>
#include <math.h>

#define N_TOK 16384
#define DIM   1024
#define HID   4096
#define NEXP  8
#define NPROJ 256
#define CLAMP_MAXD 4.605170185988091

// tile bookkeeping: sum_e ceil(cnt_e/128) <= 32768/128 + 8 = 264 tiles
#define MAX_TILES 264
#define MAX_ROWS (MAX_TILES*128)      // 33792
#define CHUNK_TILES 66
#define NCHUNK 4
#define CHUNK_ROWS (CHUNK_TILES*128)  // 8448

// meta[] layout (ints)
#define M_CNT   0   // [8] expert counts
#define M_CUR   8   // [8] fill cursors
#define M_ROWST 16  // [9] padded segment row starts
#define M_TILEST 25 // [9] segment tile starts
#define M_TOT   34  // total row tiles

typedef __bf16 bf16x8 __attribute__((ext_vector_type(8)));
typedef float  floatx4 __attribute__((ext_vector_type(4)));

__device__ __forceinline__ unsigned short f2bfbits(float f) {
  __hip_bfloat16 b = __float2bfloat16(f);
  union { __hip_bfloat16 b; unsigned short u; } c; c.b = b; return c.u;
}
__device__ __forceinline__ float bf2f(unsigned short u) {
  union { unsigned int u; float f; } c; c.u = ((unsigned int)u) << 16; return c.f;
}
__device__ __forceinline__ float gelu_exact(float z) {
  return 0.5f * z * (1.0f + erff(z * 0.70710678118654752f));
}

// direct global->LDS DMA, 16B per lane. LDS dest must be wave-uniform base;
// HW writes lane i's 16B to base + i*16.
__device__ __forceinline__ void gld16(void* lds, const void* g) {
  __builtin_amdgcn_global_load_lds(
      (const __attribute__((address_space(1))) void*)g,
      (__attribute__((address_space(3))) void*)lds, 16, 0, 0);
}

// ---------------- small prep kernels ----------------

__global__ void k_zero_meta(int* meta) { meta[threadIdx.x] = 0; }

// sim (PROJ,E) fp32 -> simn (PROJ,E) fp64, columns l2-normalized
__global__ __launch_bounds__(256) void k_simn(const float* __restrict__ sim,
                                              double* __restrict__ simn) {
  __shared__ double norms[NEXP];
  int t = threadIdx.x;
  if (t < NEXP) {
    double s = 0.0;
    for (int j = 0; j < NPROJ; ++j) { double v = (double)sim[j*NEXP + t]; s += v*v; }
    double n = sqrt(s); norms[t] = (n > 1e-12 ? n : 1e-12);
  }
  __syncthreads();
  for (int q = 0; q < (NPROJ*NEXP)/256; ++q) {
    int idx = t + q*256; int e = idx & (NEXP-1);
    simn[idx] = (double)sim[idx] / norms[e];
  }
}

__global__ __launch_bounds__(256) void k_cvtx(const float* __restrict__ x,
                                              unsigned short* __restrict__ xbf) {
  const int n4 = N_TOK*DIM/4;
  for (int i = blockIdx.x*blockDim.x + threadIdx.x; i < n4; i += gridDim.x*blockDim.x) {
    float4 v = ((const float4*)x)[i];
    ushort4 o; o.x = f2bfbits(v.x); o.y = f2bfbits(v.y); o.z = f2bfbits(v.z); o.w = f2bfbits(v.w);
    ((ushort4*)xbf)[i] = o;
  }
}

// fp32 (Z,R,C) -> bf16 (Z,C,R)
__global__ __launch_bounds__(256) void k_transpose(const float* __restrict__ in,
                                                   unsigned short* __restrict__ out,
                                                   int R, int C) {
  __shared__ float tile[32][33];
  size_t zoff = (size_t)blockIdx.z * (size_t)R * (size_t)C;
  in += zoff; out += zoff;
  int c  = blockIdx.x*32 + threadIdx.x;
  int r0 = blockIdx.y*32 + threadIdx.y;
  #pragma unroll
  for (int i = 0; i < 4; ++i)
    tile[threadIdx.y + i*8][threadIdx.x] = in[(size_t)(r0 + i*8)*C + c];
  __syncthreads();
  int r  = blockIdx.y*32 + threadIdx.x;
  int c0 = blockIdx.x*32 + threadIdx.y;
  #pragma unroll
  for (int i = 0; i < 4; ++i)
    out[(size_t)(c0 + i*8)*R + r] = f2bfbits(tile[threadIdx.x][threadIdx.y + i*8]);
}

// ---------------- gating (fp64 accumulation: top-k flip safety) ----------------
#define GT 8
__global__ __launch_bounds__(256) void k_gating(const float* __restrict__ x,
    const float* __restrict__ Wp, const float* __restrict__ bp,
    const double* __restrict__ simn, const float* __restrict__ temp,
    float* __restrict__ gates, int* __restrict__ eidx, int* __restrict__ meta) {
  __shared__ float xs[GT*DIM];
  __shared__ double wred[4][GT][9];
  int tid = threadIdx.x, lane = tid & 63, wv = tid >> 6;
  int i0 = blockIdx.x * GT;
  { const float4* src = (const float4*)(x + (size_t)i0*DIM);
    float4* dst = (float4*)xs;
    #pragma unroll
    for (int q = 0; q < GT*DIM/4/256; ++q) dst[tid + q*256] = src[tid + q*256]; }
  __syncthreads();
  double acc[GT];
  #pragma unroll
  for (int t = 0; t < GT; ++t) acc[t] = 0.0;
  const int j = tid; // proj column
  for (int d = 0; d < DIM; d += 4) {
    double w0 = (double)Wp[(d+0)*NPROJ + j];
    double w1 = (double)Wp[(d+1)*NPROJ + j];
    double w2 = (double)Wp[(d+2)*NPROJ + j];
    double w3 = (double)Wp[(d+3)*NPROJ + j];
    #pragma unroll
    for (int t = 0; t < GT; ++t) {
      float4 xv = *(const float4*)&xs[t*DIM + d];
      acc[t] += w0*(double)xv.x; acc[t] += w1*(double)xv.y;
      acc[t] += w2*(double)xv.z; acc[t] += w3*(double)xv.w;
    }
  }
  double bpj = (double)bp[j];
  double sn[NEXP];
  #pragma unroll
  for (int e = 0; e < NEXP; ++e) sn[e] = simn[j*NEXP + e];
  for (int t = 0; t < GT; ++t) {
    double v = acc[t] + bpj;
    double vals[9];
    vals[0] = v*v;
    #pragma unroll
    for (int e = 0; e < NEXP; ++e) vals[e+1] = v*sn[e];
    #pragma unroll
    for (int off = 32; off > 0; off >>= 1)
      #pragma unroll
      for (int k = 0; k < 9; ++k) vals[k] += __shfl_down(vals[k], off, 64);
    if (lane == 0)
      #pragma unroll
      for (int k = 0; k < 9; ++k) wred[wv][t][k] = vals[k];
  }
  __syncthreads();
  if (tid < GT) {
    int t = tid;
    double s[9];
    #pragma unroll
    for (int k = 0; k < 9; ++k)
      s[k] = wred[0][t][k] + wred[1][t][k] + wred[2][t][k] + wred[3][t][k];
    double den = sqrt(s[0]); if (den < 1e-12) den = 1e-12;
    double tp = (double)temp[0]; if (tp > CLAMP_MAXD) tp = CLAMP_MAXD;
    double sc = exp(tp) / den;
    double l[NEXP];
    #pragma unroll
    for (int e = 0; e < NEXP; ++e) l[e] = s[e+1]*sc;
    int iA = 0; double vA = l[0];
    for (int e = 1; e < NEXP; ++e) if (l[e] > vA) { vA = l[e]; iA = e; }
    int iB = -1; double vB = -1e300;
    for (int e = 0; e < NEXP; ++e) if (e != iA && l[e] > vB) { vB = l[e]; iB = e; }
    double ex = exp(vB - vA);
    double g0 = 1.0/(1.0+ex);
    int i = i0 + t;
    gates[2*i] = (float)g0; gates[2*i+1] = (float)(ex/(1.0+ex));
    eidx[2*i] = iA; eidx[2*i+1] = iB;
    atomicAdd(&meta[M_CNT + iA], 1); atomicAdd(&meta[M_CNT + iB], 1);
  }
}

// ---------------- routing ----------------
__global__ void k_offsets(int* meta) {
  int accT = 0;
  for (int e = 0; e < NEXP; ++e) {
    meta[M_TILEST + e] = accT;
    meta[M_ROWST + e]  = accT * 128;
    accT += (meta[M_CNT + e] + 127) >> 7;
  }
  meta[M_TILEST + NEXP] = accT;
  meta[M_ROWST + NEXP]  = accT * 128;
  meta[M_TOT] = accT;
}

__global__ void k_inittok(int* tok) { tok[blockIdx.x*256 + threadIdx.x] = 0; }

__global__ void k_fill(const int* __restrict__ eidx, int* meta,
                       int* __restrict__ tok, int* __restrict__ rowOf) {
  int i = blockIdx.x*256 + threadIdx.x;
  if (i >= N_TOK) return;
  #pragma unroll
  for (int k = 0; k < 2; ++k) {
    int e = eidx[2*i + k];
    int pos = atomicAdd(&meta[M_CUR + e], 1);
    int row = meta[M_ROWST + e] + pos;
    tok[row] = i;
    rowOf[2*i + k] = row;
  }
}

// ---------------- expert GEMM: 128x128 tile, BK=64, bf16 MFMA 16x16x32 ----------------
// LDS: unpadded 128 rows x 64 shorts (128B) per operand, filled by global_load_lds
// DMA. XOR swizzle: 16B group g of row r lives at slot (g ^ (r&7)). The DMA's
// lane->global mapping applies the permutation; fragment ds_read_b128s then hit
// bank-group 4*(gk^(m&7)) -> exact 8-lane/group spread (conflict floor).
union LdsU {
  struct { short A[128*64]; short B[128*64]; } s;  // 32 KB
  float C[32*132];                                  // epilogue transpose buffer
};

template<int ACT>
__global__ __launch_bounds__(256) void k_gemm(
    const unsigned short* __restrict__ Abase, const int* __restrict__ rowmap, int aRowOff,
    const unsigned short* __restrict__ Bbase, long bExpStride,
    const float* __restrict__ biasBase, int biasStride,
    unsigned short* __restrict__ Cbase, int ldc, int cRowOff,
    const int* __restrict__ meta, int tileBase, int K) {
  __shared__ LdsU lds;
  int rt = tileBase + blockIdx.y;
  if (rt >= meta[M_TOT]) return;
  int e = 0;
  #pragma unroll
  for (int q = 1; q < NEXP; ++q) if (rt >= meta[M_TILEST + q]) e = q;
  const unsigned short* Bexp = Bbase + (size_t)e * (size_t)bExpStride;
  int tid = threadIdx.x;
  int lane = tid & 63, wv = tid >> 6, mw = wv >> 1, nw = wv & 1;
  int ntBase = blockIdx.x * 128;
  // DMA source pointers: instr jj of wave wv covers tile rows wv*32+jj*8 .. +8
  int lr = lane >> 3;   // row within 8-row slab
  int sg = lane & 7;    // stored 16B-slot within row
  const unsigned short* aG[4]; const unsigned short* bG[4];
  #pragma unroll
  for (int jj = 0; jj < 4; ++jj) {
    int r = wv*32 + jj*8 + lr;
    int g = sg ^ (r & 7);          // global group that lands in slot sg
    int grow = rt*128 + r;
    int arow = rowmap ? rowmap[grow] : (grow - aRowOff);
    aG[jj] = Abase + (size_t)arow * (size_t)K + g*8;
    bG[jj] = Bexp + (size_t)(ntBase + r) * (size_t)K + g*8;
  }
  floatx4 acc[4][4];
  #pragma unroll
  for (int mi = 0; mi < 4; ++mi)
    #pragma unroll
    for (int ni = 0; ni < 4; ++ni) acc[mi][ni] = (floatx4){0.f,0.f,0.f,0.f};
  const int nK = K >> 6;
  for (int kt = 0; kt < nK; ++kt) {
    __syncthreads();   // prev iteration's LDS reads done before DMA overwrites
    #pragma unroll
    for (int jj = 0; jj < 4; ++jj) {
      gld16(&lds.s.A[(wv*32 + jj*8)*64], aG[jj] + (kt<<6));
      gld16(&lds.s.B[(wv*32 + jj*8)*64], bG[jj] + (kt<<6));
    }
    __syncthreads();   // compiler inserts s_waitcnt vmcnt(0) before barrier
    #pragma unroll
    for (int ks = 0; ks < 2; ++ks) {
      int gk = ks*4 + (lane >> 4);   // 16B k-group index within row
      bf16x8 af[4], bfr[4];
      #pragma unroll
      for (int mi = 0; mi < 4; ++mi) {
        int m = mw*64 + mi*16 + (lane & 15);
        af[mi] = *(const bf16x8*)&lds.s.A[m*64 + (gk ^ (m & 7))*8];
      }
      #pragma unroll
      for (int ni = 0; ni < 4; ++ni) {
        int n = nw*64 + ni*16 + (lane & 15);
        bfr[ni] = *(const bf16x8*)&lds.s.B[n*64 + (gk ^ (n & 7))*8];
      }
      #pragma unroll
      for (int mi = 0; mi < 4; ++mi)
        #pragma unroll
        for (int ni = 0; ni < 4; ++ni)
          acc[mi][ni] = __builtin_amdgcn_mfma_f32_16x16x32_bf16(af[mi], bfr[ni], acc[mi][ni], 0,0,0);
    }
  }
  // epilogue: per m-subtile, LDS transpose -> bias -> (gelu) -> bf16 16B stores
  const float* bias = biasBase + (size_t)e * (size_t)biasStride + ntBase;
  #pragma unroll
  for (int p = 0; p < 4; ++p) {
    __syncthreads();
    int lrow0 = mw*16 + ((lane>>4)<<2);
    int lcol  = nw*64 + (lane & 15);
    #pragma unroll
    for (int ni = 0; ni < 4; ++ni)
      #pragma unroll
      for (int jj = 0; jj < 4; ++jj)
        lds.C[(lrow0 + jj)*132 + lcol + ni*16] = acc[p][ni][jj];
    __syncthreads();
    #pragma unroll
    for (int q = 0; q < 2; ++q) {
      int lin = tid + q*256;
      int r = lin >> 4, c8 = lin & 15;
      float4 v0 = *(float4*)&lds.C[r*132 + c8*8];
      float4 v1 = *(float4*)&lds.C[r*132 + c8*8 + 4];
      float4 b0 = ((const float4*)bias)[c8*2];
      float4 b1 = ((const float4*)bias)[c8*2 + 1];
      v0.x += b0.x; v0.y += b0.y; v0.z += b0.z; v0.w += b0.w;
      v1.x += b1.x; v1.y += b1.y; v1.z += b1.z; v1.w += b1.w;
      if (ACT == 1) {
        v0.x = gelu_exact(v0.x); v0.y = gelu_exact(v0.y);
        v0.z = gelu_exact(v0.z); v0.w = gelu_exact(v0.w);
        v1.x = gelu_exact(v1.x); v1.y = gelu_exact(v1.y);
        v1.z = gelu_exact(v1.z); v1.w = gelu_exact(v1.w);
      }
      int gm = rt*128 + (r>>4)*64 + p*16 + (r & 15) - cRowOff;
      union { unsigned short u[8]; int4 v; } o;
      o.u[0]=f2bfbits(v0.x); o.u[1]=f2bfbits(v0.y); o.u[2]=f2bfbits(v0.z); o.u[3]=f2bfbits(v0.w);
      o.u[4]=f2bfbits(v1.x); o.u[5]=f2bfbits(v1.y); o.u[6]=f2bfbits(v1.z); o.u[7]=f2bfbits(v1.w);
      *(int4*)&Cbase[(size_t)gm*(size_t)ldc + ntBase + c8*8] = o.v;
    }
  }
}

// ---------------- combine: out = x + g0*f[r0] + g1*f[r1] ----------------
__global__ __launch_bounds__(256) void k_combine(const float* __restrict__ x,
    const unsigned short* __restrict__ f, const int* __restrict__ rowOf,
    const float* __restrict__ gates, float* __restrict__ out) {
  int i = blockIdx.x, t = threadIdx.x;
  int r0 = rowOf[2*i], r1 = rowOf[2*i+1];
  float g0 = gates[2*i], g1 = gates[2*i+1];
  float4 xv = ((const float4*)(x + (size_t)i*DIM))[t];
  ushort4 a = ((const ushort4*)(f + (size_t)r0*DIM))[t];
  ushort4 b = ((const ushort4*)(f + (size_t)r1*DIM))[t];
  float4 o;
  o.x = xv.x + g0*bf2f(a.x) + g1*bf2f(b.x);
  o.y = xv.y + g0*bf2f(a.y) + g1*bf2f(b.y);
  o.z = xv.z + g0*bf2f(a.z) + g1*bf2f(b.z);
  o.w = xv.w + g0*bf2f(a.w) + g1*bf2f(b.w);
  ((float4*)(out + (size_t)i*DIM))[t] = o;
}

// ---------------- launch ----------------
extern "C" void kernel_launch(void* const* d_in, const int* in_sizes, int n_in,
                              void* d_out, int out_size, void* d_ws, size_t ws_size,
                              hipStream_t stream) {
  const float* x    = (const float*)d_in[0];
  const float* Wp   = (const float*)d_in[1];
  const float* bp   = (const float*)d_in[2];
  const float* sim  = (const float*)d_in[3];
  const float* temp = (const float*)d_in[4];
  const float* W1   = (const float*)d_in[5];
  const float* b1   = (const float*)d_in[6];
  const float* W2   = (const float*)d_in[7];
  const float* b2   = (const float*)d_in[8];
  float* out = (float*)d_out;

  // workspace carve (~307 MB total)
  char* w = (char*)d_ws;
  auto carve = [&](size_t bytes) { char* p = w; w += (bytes + 255) & ~(size_t)255; return p; };
  int*            meta = (int*)           carve(64*sizeof(int));
  float*          gates= (float*)         carve((size_t)N_TOK*2*4);
  int*            eidx = (int*)           carve((size_t)N_TOK*2*4);
  int*            rowOf= (int*)           carve((size_t)N_TOK*2*4);
  int*            tok  = (int*)           carve((size_t)MAX_ROWS*4);
  double*         simn = (double*)        carve((size_t)NPROJ*NEXP*8);
  unsigned short* xbf  = (unsigned short*)carve((size_t)N_TOK*DIM*2);
  unsigned short* W1t  = (unsigned short*)carve((size_t)NEXP*HID*DIM*2);
  unsigned short* W2t  = (unsigned short*)carve((size_t)NEXP*DIM*HID*2);
  unsigned short* h    = (unsigned short*)carve((size_t)CHUNK_ROWS*HID*2);
  unsigned short* f    = (unsigned short*)carve((size_t)MAX_ROWS*DIM*2);

  hipLaunchKernelGGL(k_zero_meta, dim3(1), dim3(64), 0, stream, meta);
  hipLaunchKernelGGL(k_simn, dim3(1), dim3(256), 0, stream, sim, simn);
  hipLaunchKernelGGL(k_cvtx, dim3(2048), dim3(256), 0, stream, x, xbf);
  // W1 (E, D, H) -> W1t (E, H, D);  W2 (E, H, D) -> W2t (E, D, H)
  hipLaunchKernelGGL(k_transpose, dim3(HID/32, DIM/32, NEXP), dim3(32,8), 0, stream, W1, W1t, DIM, HID);
  hipLaunchKernelGGL(k_transpose, dim3(DIM/32, HID/32, NEXP), dim3(32,8), 0, stream, W2, W2t, HID, DIM);
  hipLaunchKernelGGL(k_gating, dim3(N_TOK/GT), dim3(256), 0, stream, x, Wp, bp, simn, temp, gates, eidx, meta);
  hipLaunchKernelGGL(k_offsets, dim3(1), dim3(1), 0, stream, meta);
  hipLaunchKernelGGL(k_inittok, dim3(MAX_ROWS/256), dim3(256), 0, stream, tok);
  hipLaunchKernelGGL(k_fill, dim3(N_TOK/256), dim3(256), 0, stream, eidx, meta, tok, rowOf);
  for (int c = 0; c < NCHUNK; ++c) {
    // GEMM1: h = gelu(gather(xbf) @ W1t[e]^T + b1[e]);  grid x = H tiles, y = row tiles
    hipLaunchKernelGGL((k_gemm<1>), dim3(HID/128, CHUNK_TILES), dim3(256), 0, stream,
        xbf, tok, 0, W1t, (long)HID*DIM, b1, HID,
        h, HID, c*CHUNK_ROWS, meta, c*CHUNK_TILES, DIM);
    // GEMM2: f = h @ W2t[e]^T + b2[e]
    hipLaunchKernelGGL((k_gemm<0>), dim3(DIM/128, CHUNK_TILES), dim3(256), 0, stream,
        h, (const int*)nullptr, c*CHUNK_ROWS, W2t, (long)DIM*HID, b2, DIM,
        f, DIM, 0, meta, c*CHUNK_TILES, HID);
  }
  hipLaunchKernelGGL(k_combine, dim3(N_TOK), dim3(256), 0, stream, x, f, rowOf, gates, out);
}

// Round 3
// 2483.803 us; speedup vs baseline: 1.7783x; 1.0714x over previous
//
#include <hip/hip_runtime.h>
#include <hip/hip_bf16.h>
#include <math.h>

#define N_TOK 16384
#define DIM   1024
#define HID   4096
#define NEXP  8
#define NPROJ 256
#define CLAMP_MAXD 4.605170185988091
#define CLAMP_MAXF 4.605170185988091f
#define TAU 3e-4f

// tile bookkeeping: sum_e ceil(cnt_e/128) <= 32768/128 + 8 = 264 tiles
#define MAX_TILES 264
#define MAX_ROWS (MAX_TILES*128)      // 33792
#define CHUNK_TILES 66
#define NCHUNK 4
#define CHUNK_ROWS (CHUNK_TILES*128)  // 8448

// meta[] layout (ints)
#define M_CNT   0   // [8] expert counts
#define M_CUR   8   // [8] fill cursors
#define M_ROWST 16  // [9] padded segment row starts
#define M_TILEST 25 // [9] segment tile starts
#define M_TOT   34  // total row tiles
#define M_RED   35  // redo count

typedef __bf16 bf16x8 __attribute__((ext_vector_type(8)));
typedef float  floatx4 __attribute__((ext_vector_type(4)));

__device__ __forceinline__ unsigned short f2bfbits(float f) {
  __hip_bfloat16 b = __float2bfloat16(f);
  union { __hip_bfloat16 b; unsigned short u; } c; c.b = b; return c.u;
}
__device__ __forceinline__ float bf2f(unsigned short u) {
  union { unsigned int u; float f; } c; c.u = ((unsigned int)u) << 16; return c.f;
}
__device__ __forceinline__ float gelu_exact(float z) {
  return 0.5f * z * (1.0f + erff(z * 0.70710678118654752f));
}

// direct global->LDS DMA, 16B per lane. LDS dest must be wave-uniform base;
// HW writes lane i's 16B to base + i*16.
__device__ __forceinline__ void gld16(void* lds, const void* g) {
  __builtin_amdgcn_global_load_lds(
      (const __attribute__((address_space(1))) void*)g,
      (__attribute__((address_space(3))) void*)lds, 16, 0, 0);
}

// ---------------- small prep kernels ----------------

__global__ void k_zero_meta(int* meta) { meta[threadIdx.x] = 0; }

// sim (PROJ,E) fp32 -> simn fp64 + simnf fp32, columns l2-normalized
__global__ __launch_bounds__(256) void k_simn(const float* __restrict__ sim,
                                              double* __restrict__ simn,
                                              float* __restrict__ simnf) {
  __shared__ double norms[NEXP];
  int t = threadIdx.x;
  if (t < NEXP) {
    double s = 0.0;
    for (int j = 0; j < NPROJ; ++j) { double v = (double)sim[j*NEXP + t]; s += v*v; }
    double n = sqrt(s); norms[t] = (n > 1e-12 ? n : 1e-12);
  }
  __syncthreads();
  for (int q = 0; q < (NPROJ*NEXP)/256; ++q) {
    int idx = t + q*256; int e = idx & (NEXP-1);
    double v = (double)sim[idx] / norms[e];
    simn[idx] = v; simnf[idx] = (float)v;
  }
}

// fp32 (Z,R,C) -> bf16 (Z,C,R)
__global__ __launch_bounds__(256) void k_transpose(const float* __restrict__ in,
                                                   unsigned short* __restrict__ out,
                                                   int R, int C) {
  __shared__ float tile[32][33];
  size_t zoff = (size_t)blockIdx.z * (size_t)R * (size_t)C;
  in += zoff; out += zoff;
  int c  = blockIdx.x*32 + threadIdx.x;
  int r0 = blockIdx.y*32 + threadIdx.y;
  #pragma unroll
  for (int i = 0; i < 4; ++i)
    tile[threadIdx.y + i*8][threadIdx.x] = in[(size_t)(r0 + i*8)*C + c];
  __syncthreads();
  int r  = blockIdx.y*32 + threadIdx.x;
  int c0 = blockIdx.x*32 + threadIdx.y;
  #pragma unroll
  for (int i = 0; i < 4; ++i)
    out[(size_t)(c0 + i*8)*R + r] = f2bfbits(tile[threadIdx.x][threadIdx.y + i*8]);
}

// ---------------- gating pass 1: fp32 + margin test (fused x->bf16) ----------------
// 16 tokens/block; wave w handles tokens w*4..w*4+3; lane owns proj cols 4*lane..+3.
// x-row loads are wave-uniform (scalar-path broadcast); Wp loads coalesced float4.
// Rank2-vs-rank3 margin < TAU => token pushed to fp64 redo list.
#define GT1 16
__global__ __launch_bounds__(256) void k_gating1(const float* __restrict__ x,
    const float* __restrict__ Wp, const float* __restrict__ bp,
    const float* __restrict__ simnf, const float* __restrict__ temp,
    float* __restrict__ gates, int* __restrict__ eidx, int* __restrict__ meta,
    int* __restrict__ redoList, unsigned short* __restrict__ xbf) {
  __shared__ int hist[NEXP];
  int tid = threadIdx.x, lane = tid & 63;
  int tg = __builtin_amdgcn_readfirstlane(tid >> 6);
  int i0 = blockIdx.x * GT1;
  if (tid < NEXP) hist[tid] = 0;
  // fused bf16 conversion of this block's 16 rows
  {
    const float4* src = (const float4*)(x + (size_t)i0*DIM);
    ushort4* dst = (ushort4*)(xbf + (size_t)i0*DIM);
    #pragma unroll
    for (int q = 0; q < GT1*DIM/4/256; ++q) {
      float4 v = src[tid + q*256];
      ushort4 o; o.x=f2bfbits(v.x); o.y=f2bfbits(v.y); o.z=f2bfbits(v.z); o.w=f2bfbits(v.w);
      dst[tid + q*256] = o;
    }
  }
  __syncthreads();
  const float* xr0 = x + (size_t)(i0 + tg*4 + 0)*DIM;
  const float* xr1 = x + (size_t)(i0 + tg*4 + 1)*DIM;
  const float* xr2 = x + (size_t)(i0 + tg*4 + 2)*DIM;
  const float* xr3 = x + (size_t)(i0 + tg*4 + 3)*DIM;
  float acc[4][4];
  #pragma unroll
  for (int t = 0; t < 4; ++t)
    #pragma unroll
    for (int q = 0; q < 4; ++q) acc[t][q] = 0.f;
  for (int d = 0; d < DIM; d += 4) {
    float4 xv[4];
    xv[0] = *(const float4*)&xr0[d]; xv[1] = *(const float4*)&xr1[d];
    xv[2] = *(const float4*)&xr2[d]; xv[3] = *(const float4*)&xr3[d];
    #pragma unroll
    for (int dd = 0; dd < 4; ++dd) {
      float4 wv = *(const float4*)&Wp[(size_t)(d+dd)*NPROJ + 4*lane];
      #pragma unroll
      for (int t = 0; t < 4; ++t) {
        float xs = ((const float*)&xv[t])[dd];
        acc[t][0] += xs*wv.x; acc[t][1] += xs*wv.y;
        acc[t][2] += xs*wv.z; acc[t][3] += xs*wv.w;
      }
    }
  }
  float4 bpv = *(const float4*)&bp[4*lane];
  float sn[4][8];
  #pragma unroll
  for (int q = 0; q < 4; ++q) {
    float4 a = *(const float4*)&simnf[(4*lane+q)*NEXP];
    float4 b = *(const float4*)&simnf[(4*lane+q)*NEXP + 4];
    sn[q][0]=a.x; sn[q][1]=a.y; sn[q][2]=a.z; sn[q][3]=a.w;
    sn[q][4]=b.x; sn[q][5]=b.y; sn[q][6]=b.z; sn[q][7]=b.w;
  }
  float tp = fminf(temp[0], CLAMP_MAXF);
  float esc = expf(tp);
  #pragma unroll
  for (int t = 0; t < 4; ++t) {
    float v[4];
    v[0]=acc[t][0]+bpv.x; v[1]=acc[t][1]+bpv.y; v[2]=acc[t][2]+bpv.z; v[3]=acc[t][3]+bpv.w;
    float vals[9];
    vals[0] = v[0]*v[0] + v[1]*v[1] + v[2]*v[2] + v[3]*v[3];
    #pragma unroll
    for (int e = 0; e < NEXP; ++e)
      vals[1+e] = v[0]*sn[0][e] + v[1]*sn[1][e] + v[2]*sn[2][e] + v[3]*sn[3][e];
    #pragma unroll
    for (int off = 32; off > 0; off >>= 1)
      #pragma unroll
      for (int k = 0; k < 9; ++k) vals[k] += __shfl_xor(vals[k], off, 64);
    float den = sqrtf(vals[0]); den = fmaxf(den, 1e-12f);
    float l[8];
    #pragma unroll
    for (int e = 0; e < NEXP; ++e) l[e] = vals[1+e] / den;
    int iA = 0; float vA = l[0];
    #pragma unroll
    for (int e = 1; e < NEXP; ++e) if (l[e] > vA) { vA = l[e]; iA = e; }
    int iB = -1; float vB = -1e30f;
    #pragma unroll
    for (int e = 0; e < NEXP; ++e) if (e != iA && l[e] > vB) { vB = l[e]; iB = e; }
    float vC = -1e30f;
    #pragma unroll
    for (int e = 0; e < NEXP; ++e) if (e != iA && e != iB && l[e] > vC) vC = l[e];
    if (lane == 0) {
      int i = i0 + tg*4 + t;
      if (vB - vC < TAU) {
        int p = atomicAdd(&meta[M_RED], 1);
        redoList[p] = i;
      } else {
        float ex = expf((vB - vA) * esc);
        float g0 = 1.f / (1.f + ex);
        gates[2*i] = g0; gates[2*i+1] = ex / (1.f + ex);
        eidx[2*i] = iA; eidx[2*i+1] = iB;
        atomicAdd(&hist[iA], 1); atomicAdd(&hist[iB], 1);
      }
    }
  }
  __syncthreads();
  if (tid < NEXP && hist[tid] > 0) atomicAdd(&meta[M_CNT + tid], hist[tid]);
}

// ---------------- gating pass 2: fp64 exact redo for marginal tokens ----------------
__global__ __launch_bounds__(256) void k_gredo(const float* __restrict__ x,
    const float* __restrict__ Wp, const float* __restrict__ bp,
    const double* __restrict__ simn, const float* __restrict__ temp,
    float* __restrict__ gates, int* __restrict__ eidx, int* __restrict__ meta,
    const int* __restrict__ redoList) {
  __shared__ double wred[4][9];
  int nredo = meta[M_RED];
  int tid = threadIdx.x, lane = tid & 63, wv = tid >> 6;
  for (int r = blockIdx.x; r < nredo; r += gridDim.x) {
    int i = redoList[r];
    const float* xr = x + (size_t)i*DIM;
    int j = tid;
    double acc = 0.0;
    for (int d = 0; d < DIM; d += 4) {
      float4 xv = *(const float4*)&xr[d];
      acc += (double)xv.x * (double)Wp[(size_t)(d+0)*NPROJ + j];
      acc += (double)xv.y * (double)Wp[(size_t)(d+1)*NPROJ + j];
      acc += (double)xv.z * (double)Wp[(size_t)(d+2)*NPROJ + j];
      acc += (double)xv.w * (double)Wp[(size_t)(d+3)*NPROJ + j];
    }
    double v = acc + (double)bp[j];
    double vals[9];
    vals[0] = v*v;
    #pragma unroll
    for (int e = 0; e < NEXP; ++e) vals[1+e] = v * simn[j*NEXP + e];
    #pragma unroll
    for (int off = 32; off > 0; off >>= 1)
      #pragma unroll
      for (int k = 0; k < 9; ++k) vals[k] += __shfl_xor(vals[k], off, 64);
    if (lane == 0)
      #pragma unroll
      for (int k = 0; k < 9; ++k) wred[wv][k] = vals[k];
    __syncthreads();
    if (tid == 0) {
      double s[9];
      #pragma unroll
      for (int k = 0; k < 9; ++k)
        s[k] = wred[0][k] + wred[1][k] + wred[2][k] + wred[3][k];
      double den = sqrt(s[0]); if (den < 1e-12) den = 1e-12;
      double tp = (double)temp[0]; if (tp > CLAMP_MAXD) tp = CLAMP_MAXD;
      double sc = exp(tp) / den;
      double l[NEXP];
      #pragma unroll
      for (int e = 0; e < NEXP; ++e) l[e] = s[e+1]*sc;
      int iA = 0; double vA = l[0];
      for (int e = 1; e < NEXP; ++e) if (l[e] > vA) { vA = l[e]; iA = e; }
      int iB = -1; double vB = -1e300;
      for (int e = 0; e < NEXP; ++e) if (e != iA && l[e] > vB) { vB = l[e]; iB = e; }
      double ex = exp(vB - vA);
      double g0 = 1.0/(1.0+ex);
      gates[2*i] = (float)g0; gates[2*i+1] = (float)(ex/(1.0+ex));
      eidx[2*i] = iA; eidx[2*i+1] = iB;
      atomicAdd(&meta[M_CNT + iA], 1); atomicAdd(&meta[M_CNT + iB], 1);
    }
    __syncthreads();
  }
}

// ---------------- routing ----------------
__global__ void k_offsets(int* meta) {
  int accT = 0;
  for (int e = 0; e < NEXP; ++e) {
    meta[M_TILEST + e] = accT;
    meta[M_ROWST + e]  = accT * 128;
    accT += (meta[M_CNT + e] + 127) >> 7;
  }
  meta[M_TILEST + NEXP] = accT;
  meta[M_ROWST + NEXP]  = accT * 128;
  meta[M_TOT] = accT;
}

__global__ void k_inittok(int* tok) { tok[blockIdx.x*256 + threadIdx.x] = 0; }

__global__ void k_fill(const int* __restrict__ eidx, int* meta,
                       int* __restrict__ tok, int* __restrict__ rowOf) {
  int i = blockIdx.x*256 + threadIdx.x;
  if (i >= N_TOK) return;
  #pragma unroll
  for (int k = 0; k < 2; ++k) {
    int e = eidx[2*i + k];
    int pos = atomicAdd(&meta[M_CUR + e], 1);
    int row = meta[M_ROWST + e] + pos;
    tok[row] = i;
    rowOf[2*i + k] = row;
  }
}

// ---------------- expert GEMM: 128x128 tile, BK=64, bf16 MFMA 16x16x32 ----------------
// LDS: unpadded 128 rows x 64 shorts (128B) per operand, filled by global_load_lds
// DMA. XOR swizzle: 16B group g of row r lives at slot (g ^ (r&7)). The DMA's
// lane->global mapping applies the permutation; fragment ds_read_b128s then hit
// bank-group 4*(gk^(m&7)) -> exact 8-lane/group spread (conflict floor).
union LdsU {
  struct { short A[128*64]; short B[128*64]; } s;  // 32 KB
  float C[32*132];                                  // epilogue transpose buffer
};

template<int ACT>
__global__ __launch_bounds__(256) void k_gemm(
    const unsigned short* __restrict__ Abase, const int* __restrict__ rowmap, int aRowOff,
    const unsigned short* __restrict__ Bbase, long bExpStride,
    const float* __restrict__ biasBase, int biasStride,
    unsigned short* __restrict__ Cbase, int ldc, int cRowOff,
    const int* __restrict__ meta, int tileBase, int K) {
  __shared__ LdsU lds;
  int rt = tileBase + blockIdx.y;
  if (rt >= meta[M_TOT]) return;
  int e = 0;
  #pragma unroll
  for (int q = 1; q < NEXP; ++q) if (rt >= meta[M_TILEST + q]) e = q;
  const unsigned short* Bexp = Bbase + (size_t)e * (size_t)bExpStride;
  int tid = threadIdx.x;
  int lane = tid & 63, wv = tid >> 6, mw = wv >> 1, nw = wv & 1;
  int ntBase = blockIdx.x * 128;
  // DMA source pointers: instr jj of wave wv covers tile rows wv*32+jj*8 .. +8
  int lr = lane >> 3;   // row within 8-row slab
  int sg = lane & 7;    // stored 16B-slot within row
  const unsigned short* aG[4]; const unsigned short* bG[4];
  #pragma unroll
  for (int jj = 0; jj < 4; ++jj) {
    int r = wv*32 + jj*8 + lr;
    int g = sg ^ (r & 7);          // global group that lands in slot sg
    int grow = rt*128 + r;
    int arow = rowmap ? rowmap[grow] : (grow - aRowOff);
    aG[jj] = Abase + (size_t)arow * (size_t)K + g*8;
    bG[jj] = Bexp + (size_t)(ntBase + r) * (size_t)K + g*8;
  }
  floatx4 acc[4][4];
  #pragma unroll
  for (int mi = 0; mi < 4; ++mi)
    #pragma unroll
    for (int ni = 0; ni < 4; ++ni) acc[mi][ni] = (floatx4){0.f,0.f,0.f,0.f};
  const int nK = K >> 6;
  for (int kt = 0; kt < nK; ++kt) {
    __syncthreads();   // prev iteration's LDS reads done before DMA overwrites
    #pragma unroll
    for (int jj = 0; jj < 4; ++jj) {
      gld16(&lds.s.A[(wv*32 + jj*8)*64], aG[jj] + (kt<<6));
      gld16(&lds.s.B[(wv*32 + jj*8)*64], bG[jj] + (kt<<6));
    }
    __syncthreads();   // compiler inserts s_waitcnt vmcnt(0) before barrier
    #pragma unroll
    for (int ks = 0; ks < 2; ++ks) {
      int gk = ks*4 + (lane >> 4);   // 16B k-group index within row
      bf16x8 af[4], bfr[4];
      #pragma unroll
      for (int mi = 0; mi < 4; ++mi) {
        int m = mw*64 + mi*16 + (lane & 15);
        af[mi] = *(const bf16x8*)&lds.s.A[m*64 + (gk ^ (m & 7))*8];
      }
      #pragma unroll
      for (int ni = 0; ni < 4; ++ni) {
        int n = nw*64 + ni*16 + (lane & 15);
        bfr[ni] = *(const bf16x8*)&lds.s.B[n*64 + (gk ^ (n & 7))*8];
      }
      #pragma unroll
      for (int mi = 0; mi < 4; ++mi)
        #pragma unroll
        for (int ni = 0; ni < 4; ++ni)
          acc[mi][ni] = __builtin_amdgcn_mfma_f32_16x16x32_bf16(af[mi], bfr[ni], acc[mi][ni], 0,0,0);
    }
  }
  // epilogue: per m-subtile, LDS transpose -> bias -> (gelu) -> bf16 16B stores
  const float* bias = biasBase + (size_t)e * (size_t)biasStride + ntBase;
  #pragma unroll
  for (int p = 0; p < 4; ++p) {
    __syncthreads();
    int lrow0 = mw*16 + ((lane>>4)<<2);
    int lcol  = nw*64 + (lane & 15);
    #pragma unroll
    for (int ni = 0; ni < 4; ++ni)
      #pragma unroll
      for (int jj = 0; jj < 4; ++jj)
        lds.C[(lrow0 + jj)*132 + lcol + ni*16] = acc[p][ni][jj];
    __syncthreads();
    #pragma unroll
    for (int q = 0; q < 2; ++q) {
      int lin = tid + q*256;
      int r = lin >> 4, c8 = lin & 15;
      float4 v0 = *(float4*)&lds.C[r*132 + c8*8];
      float4 v1 = *(float4*)&lds.C[r*132 + c8*8 + 4];
      float4 b0 = ((const float4*)bias)[c8*2];
      float4 b1 = ((const float4*)bias)[c8*2 + 1];
      v0.x += b0.x; v0.y += b0.y; v0.z += b0.z; v0.w += b0.w;
      v1.x += b1.x; v1.y += b1.y; v1.z += b1.z; v1.w += b1.w;
      if (ACT == 1) {
        v0.x = gelu_exact(v0.x); v0.y = gelu_exact(v0.y);
        v0.z = gelu_exact(v0.z); v0.w = gelu_exact(v0.w);
        v1.x = gelu_exact(v1.x); v1.y = gelu_exact(v1.y);
        v1.z = gelu_exact(v1.z); v1.w = gelu_exact(v1.w);
      }
      int gm = rt*128 + (r>>4)*64 + p*16 + (r & 15) - cRowOff;
      union { unsigned short u[8]; int4 v; } o;
      o.u[0]=f2bfbits(v0.x); o.u[1]=f2bfbits(v0.y); o.u[2]=f2bfbits(v0.z); o.u[3]=f2bfbits(v0.w);
      o.u[4]=f2bfbits(v1.x); o.u[5]=f2bfbits(v1.y); o.u[6]=f2bfbits(v1.z); o.u[7]=f2bfbits(v1.w);
      *(int4*)&Cbase[(size_t)gm*(size_t)ldc + ntBase + c8*8] = o.v;
    }
  }
}

// ---------------- combine: out = x + g0*f[r0] + g1*f[r1] ----------------
__global__ __launch_bounds__(256) void k_combine(const float* __restrict__ x,
    const unsigned short* __restrict__ f, const int* __restrict__ rowOf,
    const float* __restrict__ gates, float* __restrict__ out) {
  int i = blockIdx.x, t = threadIdx.x;
  int r0 = rowOf[2*i], r1 = rowOf[2*i+1];
  float g0 = gates[2*i], g1 = gates[2*i+1];
  float4 xv = ((const float4*)(x + (size_t)i*DIM))[t];
  ushort4 a = ((const ushort4*)(f + (size_t)r0*DIM))[t];
  ushort4 b = ((const ushort4*)(f + (size_t)r1*DIM))[t];
  float4 o;
  o.x = xv.x + g0*bf2f(a.x) + g1*bf2f(b.x);
  o.y = xv.y + g0*bf2f(a.y) + g1*bf2f(b.y);
  o.z = xv.z + g0*bf2f(a.z) + g1*bf2f(b.z);
  o.w = xv.w + g0*bf2f(a.w) + g1*bf2f(b.w);
  ((float4*)(out + (size_t)i*DIM))[t] = o;
}

// ---------------- launch ----------------
extern "C" void kernel_launch(void* const* d_in, const int* in_sizes, int n_in,
                              void* d_out, int out_size, void* d_ws, size_t ws_size,
                              hipStream_t stream) {
  const float* x    = (const float*)d_in[0];
  const float* Wp   = (const float*)d_in[1];
  const float* bp   = (const float*)d_in[2];
  const float* sim  = (const float*)d_in[3];
  const float* temp = (const float*)d_in[4];
  const float* W1   = (const float*)d_in[5];
  const float* b1   = (const float*)d_in[6];
  const float* W2   = (const float*)d_in[7];
  const float* b2   = (const float*)d_in[8];
  float* out = (float*)d_out;

  // workspace carve (~307 MB total)
  char* w = (char*)d_ws;
  auto carve = [&](size_t bytes) { char* p = w; w += (bytes + 255) & ~(size_t)255; return p; };
  int*            meta = (int*)           carve(64*sizeof(int));
  float*          gates= (float*)         carve((size_t)N_TOK*2*4);
  int*            eidx = (int*)           carve((size_t)N_TOK*2*4);
  int*            rowOf= (int*)           carve((size_t)N_TOK*2*4);
  int*            tok  = (int*)           carve((size_t)MAX_ROWS*4);
  int*            redoL= (int*)           carve((size_t)N_TOK*4);
  double*         simn = (double*)        carve((size_t)NPROJ*NEXP*8);
  float*          simnf= (float*)         carve((size_t)NPROJ*NEXP*4);
  unsigned short* xbf  = (unsigned short*)carve((size_t)N_TOK*DIM*2);
  unsigned short* W1t  = (unsigned short*)carve((size_t)NEXP*HID*DIM*2);
  unsigned short* W2t  = (unsigned short*)carve((size_t)NEXP*DIM*HID*2);
  unsigned short* h    = (unsigned short*)carve((size_t)CHUNK_ROWS*HID*2);
  unsigned short* f    = (unsigned short*)carve((size_t)MAX_ROWS*DIM*2);

  hipLaunchKernelGGL(k_zero_meta, dim3(1), dim3(64), 0, stream, meta);
  hipLaunchKernelGGL(k_simn, dim3(1), dim3(256), 0, stream, sim, simn, simnf);
  // W1 (E, D, H) -> W1t (E, H, D);  W2 (E, H, D) -> W2t (E, D, H)
  hipLaunchKernelGGL(k_transpose, dim3(HID/32, DIM/32, NEXP), dim3(32,8), 0, stream, W1, W1t, DIM, HID);
  hipLaunchKernelGGL(k_transpose, dim3(DIM/32, HID/32, NEXP), dim3(32,8), 0, stream, W2, W2t, HID, DIM);
  hipLaunchKernelGGL(k_gating1, dim3(N_TOK/GT1), dim3(256), 0, stream,
                     x, Wp, bp, simnf, temp, gates, eidx, meta, redoL, xbf);
  hipLaunchKernelGGL(k_gredo, dim3(128), dim3(256), 0, stream,
                     x, Wp, bp, simn, temp, gates, eidx, meta, redoL);
  hipLaunchKernelGGL(k_offsets, dim3(1), dim3(1), 0, stream, meta);
  hipLaunchKernelGGL(k_inittok, dim3(MAX_ROWS/256), dim3(256), 0, stream, tok);
  hipLaunchKernelGGL(k_fill, dim3(N_TOK/256), dim3(256), 0, stream, eidx, meta, tok, rowOf);
  for (int c = 0; c < NCHUNK; ++c) {
    // GEMM1: h = gelu(gather(xbf) @ W1t[e]^T + b1[e]);  grid x = H tiles, y = row tiles
    hipLaunchKernelGGL((k_gemm<1>), dim3(HID/128, CHUNK_TILES), dim3(256), 0, stream,
        xbf, tok, 0, W1t, (long)HID*DIM, b1, HID,
        h, HID, c*CHUNK_ROWS, meta, c*CHUNK_TILES, DIM);
    // GEMM2: f = h @ W2t[e]^T + b2[e]
    hipLaunchKernelGGL((k_gemm<0>), dim3(DIM/128, CHUNK_TILES), dim3(256), 0, stream,
        h, (const int*)nullptr, c*CHUNK_ROWS, W2t, (long)DIM*HID, b2, DIM,
        f, DIM, 0, meta, c*CHUNK_TILES, HID);
  }
  hipLaunchKernelGGL(k_combine, dim3(N_TOK), dim3(256), 0, stream, x, f, rowOf, gates, out);
}